// Round 20
// baseline (757.690 us; speedup 1.0000x reference)
//
#include <hip/hip_runtime.h>
#include <cstddef>
#include <cstdint>

#define DD 300
#define HH 600
#define LL 5
#define NGG 512
#define KP1 320     // padded K for GEMM1 (fp16 A row stride)
#define KP2 608     // padded K for GEMM2 (fp16 Z1 row stride)
#define NP1 640     // padded N of W1^T (600 -> 5 col-blocks of 128)
#define NP2 384     // padded N of W2^T (300 -> 3 col-blocks of 128)
#define Z2LD 304    // fp16 z2/h row stride
#define CLD 304     // fp16 combo row stride (16B-aligned rows)

typedef unsigned short u16;
typedef _Float16 f16x8 __attribute__((ext_vector_type(8)));
typedef _Float16 h2 __attribute__((ext_vector_type(2)));
typedef float f32x4 __attribute__((ext_vector_type(4)));

__device__ __forceinline__ u16 f2h(float v)
{
    _Float16 h = (_Float16)v; u16 u; __builtin_memcpy(&u, &h, 2); return u;
}
__device__ __forceinline__ float h2f(u16 u)
{
    _Float16 h; __builtin_memcpy(&h, &u, 2); return (float)h;
}

__device__ __forceinline__ void g2l16(const void* g, void* l)
{
    __builtin_amdgcn_global_load_lds(
        (const __attribute__((address_space(1))) void*)g,
        (__attribute__((address_space(3))) void*)l, 16, 0, 0);
}

// BatchNorm scale/shift from raw column stats
__device__ __forceinline__ void bn_from_stats(float s, float q, float g, float be,
                                              float invn, float& sc, float& sh)
{
    float mu = s * invn;
    float var = q * invn - mu * mu;
    float rs = rsqrtf(var + 1e-5f);
    sc = rs * g;
    sh = be - mu * sc;
}

// ---------------- fused Atom encoder + combo table builder ----------------
__global__ __launch_bounds__(320) void atom_combo(const int* __restrict__ x,
    const float* __restrict__ emb, const float* __restrict__ bond,
    u16* __restrict__ z2, u16* __restrict__ combo, int N)
{
    int b = blockIdx.x;
    int t = threadIdx.x;
    if (b < N) {
        __shared__ int xi[9];
        if (t < 9) xi[t] = x[b * 9 + t] + t * 64;
        __syncthreads();
        if (t >= Z2LD) return;
        if (t >= DD) { z2[(size_t)b * Z2LD + t] = 0; return; }
        float s = 0.f;
#pragma unroll
        for (int f = 0; f < 9; ++f) s += emb[(size_t)xi[f] * DD + t];
        z2[(size_t)b * Z2LD + t] = f2h(s);
    } else {
        int blk = b - N;                // l*512 + code
        int l = blk >> 9, code = blk & 511;
        if (t >= CLD) return;
        u16 val = 0;
        if (t < DD) {
            const float* bl = bond + (size_t)l * 24 * DD;
            float v = bl[(size_t)(code & 7) * DD + t]
                    + bl[(size_t)(8 + ((code >> 3) & 7)) * DD + t]
                    + bl[(size_t)(16 + (code >> 6)) * DD + t];
            val = f2h(v);
        }
        combo[(size_t)blk * CLD + t] = val;
    }
}

// ---------------- CSR build ----------------
__global__ void csr_count(const int* __restrict__ dst, int E, int* __restrict__ cnt)
{
    int i = blockIdx.x * blockDim.x + threadIdx.x;
    int stride = gridDim.x * blockDim.x;
    for (; i < E; i += stride) atomicAdd(&cnt[dst[i]], 1);
}

__global__ __launch_bounds__(1024) void scan_kernel(const int* __restrict__ cnt,
    int* __restrict__ rowptr, int n)
{
    __shared__ int buf[1024];
    int t = threadIdx.x;
    int carry = 0;
    for (int base = 0; base < n; base += 1024) {
        int v = (base + t < n) ? cnt[base + t] : 0;
        buf[t] = v;
        __syncthreads();
        for (int off = 1; off < 1024; off <<= 1) {
            int x = (t >= off) ? buf[t - off] : 0;
            __syncthreads();
            buf[t] += x;
            __syncthreads();
        }
        if (base + t < n) rowptr[base + t] = buf[t] - v + carry;
        int total = buf[1023];
        __syncthreads();
        carry += total;
    }
    if (t == 0) rowptr[n] = carry;
}

__global__ void csr_fill(const int* __restrict__ src, const int* __restrict__ dst,
    const int* __restrict__ ea, const int* __restrict__ rowptr,
    int* __restrict__ cursor, int* __restrict__ rec, int E)
{
    int i = blockIdx.x * blockDim.x + threadIdx.x;
    int stride = gridDim.x * blockDim.x;
    for (; i < E; i += stride) {
        int d = dst[i];
        int pos = rowptr[d] + atomicAdd(&cursor[d], 1);
        int code = ea[i * 3] | (ea[i * 3 + 1] << 3) | (ea[i * 3 + 2] << 6);
        rec[pos] = src[i] | (code << 20);
    }
}

// ---------------- LDS-tiled weight transpose -> fp16, zero-padded ----------------
__global__ __launch_bounds__(256) void w_prep_t(const float* __restrict__ W,
    int K, int N, int KPp, int NPp, int ktiles, u16* __restrict__ Thi)
{
    __shared__ float tile[64][65];
    int ntiles = NPp >> 6;
    int blk = blockIdx.x;
    int l = blk / (ktiles * ntiles);
    int rem = blk % (ktiles * ntiles);
    int k0 = (rem / ntiles) << 6;
    int n0 = (rem % ntiles) << 6;
    int tn = threadIdx.x & 63;
    int tg = threadIdx.x >> 6;
    const float* Wl = W + (size_t)l * K * N;
    for (int kk = tg; kk < 64; kk += 4) {
        int gk = k0 + kk, gn = n0 + tn;
        tile[kk][tn] = (gk < K && gn < N) ? Wl[(size_t)gk * N + gn] : 0.f;
    }
    __syncthreads();
    for (int nn = tg; nn < 64; nn += 4) {
        int gn = n0 + nn, gk = k0 + tn;
        if (gk < KPp) {
            size_t o = ((size_t)l * NPp + gn) * KPp + gk;
            Thi[o] = f2h(tile[tn][nn]);
        }
    }
}

// ---------------- fused BN(prev)+ReLU + aggregate + GIN update -> fp16 A1 ----------------
template <bool AFF>
__global__ __launch_bounds__(256) void agg_kernel(const u16* __restrict__ z2,
    const int* __restrict__ rec, const int* __restrict__ rowptr,
    const u16* __restrict__ combo_l,
    const float* __restrict__ sc, const float* __restrict__ sh,
    const float* __restrict__ eps, int l, u16* __restrict__ A1)
{
    __shared__ float part[6][304];
    int n = blockIdx.x;
    int t = threadIdx.x;
    int eo = t / 38, ch = t - eo * 38;
    int d0 = ch * 8;
    int beg = rowptr[n], end = rowptr[n + 1];

    if (eo < 6) {
        float acc[8] = {0.f, 0.f, 0.f, 0.f, 0.f, 0.f, 0.f, 0.f};
        h2 scp[4], shp[4];
        const h2 zz = {(_Float16)0.f, (_Float16)0.f};
        if (AFF) {
#pragma unroll
            for (int j = 0; j < 4; ++j) {
                scp[j] = (h2){(_Float16)sc[d0 + 2 * j], (_Float16)sc[d0 + 2 * j + 1]};
                shp[j] = (h2){(_Float16)sh[d0 + 2 * j], (_Float16)sh[d0 + 2 * j + 1]};
            }
        }
        int i = beg + eo;
        for (; i + 6 < end; i += 12) {         // unroll 2 (slot stride 6)
            int r0 = rec[i], r1 = rec[i + 6];
            uint4 hv0 = *(const uint4*)(z2 + (size_t)(r0 & 0xFFFFF) * Z2LD + d0);
            uint4 cv0 = *(const uint4*)(combo_l + (size_t)(((unsigned)r0) >> 20) * CLD + d0);
            uint4 hv1 = *(const uint4*)(z2 + (size_t)(r1 & 0xFFFFF) * Z2LD + d0);
            uint4 cv1 = *(const uint4*)(combo_l + (size_t)(((unsigned)r1) >> 20) * CLD + d0);
            const h2* hp0 = (const h2*)&hv0; const h2* cp0 = (const h2*)&cv0;
            const h2* hp1 = (const h2*)&hv1; const h2* cp1 = (const h2*)&cv1;
#pragma unroll
            for (int j = 0; j < 4; ++j) {
                h2 a0 = hp0[j], a1 = hp1[j];
                if (AFF) {
                    a0 = __builtin_elementwise_max(a0 * scp[j] + shp[j], zz);
                    a1 = __builtin_elementwise_max(a1 * scp[j] + shp[j], zz);
                }
                h2 m0 = __builtin_elementwise_max(a0 + cp0[j], zz);
                h2 m1 = __builtin_elementwise_max(a1 + cp1[j], zz);
                acc[2 * j]     += (float)m0.x + (float)m1.x;
                acc[2 * j + 1] += (float)m0.y + (float)m1.y;
            }
        }
        for (; i < end; i += 6) {
            int r0 = rec[i];
            uint4 hv0 = *(const uint4*)(z2 + (size_t)(r0 & 0xFFFFF) * Z2LD + d0);
            uint4 cv0 = *(const uint4*)(combo_l + (size_t)(((unsigned)r0) >> 20) * CLD + d0);
            const h2* hp0 = (const h2*)&hv0; const h2* cp0 = (const h2*)&cv0;
#pragma unroll
            for (int j = 0; j < 4; ++j) {
                h2 a0 = hp0[j];
                if (AFF) a0 = __builtin_elementwise_max(a0 * scp[j] + shp[j], zz);
                h2 m0 = __builtin_elementwise_max(a0 + cp0[j], zz);
                acc[2 * j]     += (float)m0.x;
                acc[2 * j + 1] += (float)m0.y;
            }
        }
        *(float4*)&part[eo][d0]     = *(const float4*)&acc[0];
        *(float4*)&part[eo][d0 + 4] = *(const float4*)&acc[4];
    }
    __syncthreads();

    if (t < 152) {
        float se = 1.0f + eps[l];
        int d = t * 2;
#pragma unroll
        for (int k = 0; k < 2; ++k) {
            int dd = d + k;
            float s = part[0][dd] + part[1][dd] + part[2][dd]
                    + part[3][dd] + part[4][dd] + part[5][dd];
            float hn = h2f(z2[(size_t)n * Z2LD + dd]);
            if (AFF) hn = fmaxf(fmaf(hn, sc[dd], sh[dd]), 0.f);
            A1[(size_t)n * KP1 + dd] = f2h(fmaf(se, hn, s));
        }
    } else if (t < 160) {
        int d = 304 + (t - 152) * 2;
        A1[(size_t)n * KP1 + d] = 0;
        A1[(size_t)n * KP1 + d + 1] = 0;
    }
}

// ---------------- f16 MFMA GEMM: (128*RM)x128 tile, 3-buffer B + 3-deep A pipeline -----
// RM=2: 256-row block, each wave 128x32, 16 MFMAs per barrier (2x amortization).
// FUSE: BN1+ReLU on A from raw stats (R19-proven prologue). Counted vmcnt rederived
// for RM A-loads/body: steady vmcnt(2RM+1), tails vmcnt(RM+1)/vmcnt(0).
template <bool FUSE, int RM>
__global__ __launch_bounds__(512, 2) void gemm_rs(
    const u16* __restrict__ Af, int lda,
    const u16* __restrict__ Bw,
    const float* __restrict__ bias,
    const float* __restrict__ csA, const float* __restrict__ csqA,
    const float* __restrict__ gA, const float* __restrict__ beA, float invn,
    u16* __restrict__ O, int ldc, int M, int N, int ksteps,
    float* __restrict__ cs, float* __restrict__ csq, int ncol, int nwg)
{
    __shared__ __align__(16) u16 As[2][4][128 * RM][8];
    __shared__ __align__(16) u16 Bs[3][4][128][8];
    __shared__ float sc_s[FUSE ? 640 : 1], sh_s[FUSE ? 640 : 1];

    const int t = threadIdx.x;
    const int lane = t & 63, w = t >> 6;
    const int l15 = lane & 15, l4 = lane >> 4;
    const int wr = w >> 2, wc = w & 3;          // wave tile: (64*RM) rows x 32 cols

    // bijective XCD swizzle (m204)
    int orig = blockIdx.x;
    int q8 = nwg >> 3, r8 = nwg & 7;
    int xcd = orig & 7, i8 = orig >> 3;
    int wgid = (xcd < r8 ? xcd * (q8 + 1) : r8 * (q8 + 1) + (xcd - r8) * q8) + i8;
    const int col0 = (wgid % ncol) * 128;
    const int row0 = (wgid / ncol) * (128 * RM);

    if (FUSE) {
        for (int c = t; c < lda; c += 512) {
            float a = 0.f, b = 0.f;
            if (c < HH) bn_from_stats(csA[c], csqA[c], gA[c], beA[c], invn, a, b);
            sc_s[c] = a; sh_s[c] = b;
        }
    }

    const int arow = t >> 2;            // 0..127
    const int kg   = t & 3;             // 0..3
    const int k8   = kg * 8;
    const u16* aptr = Af + (size_t)(row0 + arow) * lda + k8;

    const int bkg = w >> 1, bch = w & 1;
    const u16* bptr = Bw + (size_t)(col0 + bch * 64 + lane) * lda + bkg * 8;

    auto loadAv = [&](int ks, uint4 (&pv)[RM]) {
#pragma unroll
        for (int rr = 0; rr < RM; ++rr)
            pv[rr] = *(const uint4*)(aptr + (size_t)rr * 128 * lda + ks * 32);
    };
    auto issueB = [&](int ks, int buf) {
        g2l16(bptr + ks * 32, &Bs[buf][bkg][bch * 64][0]);
    };
    auto writeAv = [&](int ks, int buf, uint4 (&pv)[RM]) {
#pragma unroll
        for (int rr = 0; rr < RM; ++rr) {
            if (FUSE) {
                const u16* hp = (const u16*)&pv[rr];
                u16 oh[8];
#pragma unroll
                for (int j = 0; j < 8; ++j) {
                    int c = ks * 32 + k8 + j;
                    float xv = fmaxf(fmaf(h2f(hp[j]), sc_s[c], sh_s[c]), 0.f);
                    oh[j] = f2h(xv);
                }
                *(uint4*)&As[buf][kg][rr * 128 + arow][0] = *(const uint4*)oh;
            } else {
                *(uint4*)&As[buf][kg][rr * 128 + arow][0] = pv[rr];
            }
        }
    };

    f32x4 acc[4 * RM][2];
#pragma unroll
    for (int i = 0; i < 4 * RM; ++i)
#pragma unroll
        for (int j = 0; j < 2; ++j) acc[i][j] = (f32x4){0.f, 0.f, 0.f, 0.f};

    uint4 pvA[RM], pvB[RM], pvC[RM];
    __syncthreads();                    // sc_s visible
    // prologue (ksteps >= 3): issue order A(0), B(0), B(1), A(1), A(2)
    loadAv(0, pvA);
    issueB(0, 0);
    issueB(1, 1);
    loadAv(1, pvB);
    loadAv(2, pvC);
    writeAv(0, 0, pvA);                 // compiler waits for A(0)
    if constexpr (RM == 2) asm volatile("s_waitcnt vmcnt(5) lgkmcnt(0)" ::: "memory");
    else                   asm volatile("s_waitcnt vmcnt(3) lgkmcnt(0)" ::: "memory");
    __builtin_amdgcn_s_barrier();

    int cur = 0, rb = 0, tb = 2;
    auto body = [&](int ks, uint4 (&hold)[RM], uint4 (&fill)[RM]) {
        const bool more1 = (ks + 1 < ksteps), more2 = (ks + 2 < ksteps),
                   more3 = (ks + 3 < ksteps);
        if (more2) issueB(ks + 2, tb);
        if (more3) loadAv(ks + 3, fill);

        f16x8 a[4 * RM], b[2];
#pragma unroll
        for (int i = 0; i < 4 * RM; ++i) {
            int r = wr * (64 * RM) + i * 16 + l15;
            a[i] = *(const f16x8*)As[cur][l4][r];
        }
#pragma unroll
        for (int i = 0; i < 2; ++i) {
            int c = wc * 32 + i * 16 + l15;
            b[i] = *(const f16x8*)Bs[rb][l4][c];
        }
#pragma unroll
        for (int mi = 0; mi < 4 * RM; ++mi)
#pragma unroll
            for (int ni = 0; ni < 2; ++ni)
                acc[mi][ni] = __builtin_amdgcn_mfma_f32_16x16x32_f16(a[mi], b[ni], acc[mi][ni], 0, 0, 0);

        if (more1) {
            writeAv(ks + 1, cur ^ 1, hold);   // implicit wait for A(ks+1)
            // drain B(ks+1); younger: A(ks+2)[RM], B(ks+2)[1], A(ks+3)[RM]
            if (more3) {
                if constexpr (RM == 2) asm volatile("s_waitcnt vmcnt(5) lgkmcnt(0)" ::: "memory");
                else                   asm volatile("s_waitcnt vmcnt(3) lgkmcnt(0)" ::: "memory");
            } else if (more2) {
                if constexpr (RM == 2) asm volatile("s_waitcnt vmcnt(3) lgkmcnt(0)" ::: "memory");
                else                   asm volatile("s_waitcnt vmcnt(2) lgkmcnt(0)" ::: "memory");
            } else {
                asm volatile("s_waitcnt vmcnt(0) lgkmcnt(0)" ::: "memory");
            }
            __builtin_amdgcn_s_barrier();
        }
        cur ^= 1;
        rb = (rb == 2) ? 0 : rb + 1;
        tb = (tb == 2) ? 0 : tb + 1;
    };
    for (int k = 0; k < ksteps; k += 3) {
        body(k, pvB, pvA);
        if (k + 1 < ksteps) body(k + 1, pvC, pvB);
        if (k + 2 < ksteps) body(k + 2, pvA, pvC);
    }

    // epilogue: + bias, fp16 store + fused column stats
    float colS[2] = {0.f, 0.f}, colQ[2] = {0.f, 0.f};
#pragma unroll
    for (int ni = 0; ni < 2; ++ni) {
        int gc = col0 + wc * 32 + ni * 16 + l15;
        float bb = (gc < N) ? bias[gc] : 0.f;
#pragma unroll
        for (int mi = 0; mi < 4 * RM; ++mi)
#pragma unroll
            for (int r = 0; r < 4; ++r) {
                int gr = row0 + wr * (64 * RM) + mi * 16 + l4 * 4 + r;
                if (gr >= M) continue;
                if (gc < N) {
                    float val = acc[mi][ni][r] + bb;
                    O[(size_t)gr * ldc + gc] = f2h(val);
                    colS[ni] += val;
                    colQ[ni] += val * val;
                } else if (gc < ldc) {
                    O[(size_t)gr * ldc + gc] = 0;
                }
            }
    }
#pragma unroll
    for (int ni = 0; ni < 2; ++ni) {
        float s = colS[ni], q = colQ[ni];
        s += __shfl_xor(s, 16); s += __shfl_xor(s, 32);
        q += __shfl_xor(q, 16); q += __shfl_xor(q, 32);
        int gc = col0 + wc * 32 + ni * 16 + l15;
        if (l4 == 0 && gc < N) {
            atomicAdd(&cs[gc], s);
            atomicAdd(&csq[gc], q);
        }
    }
}

// ---------------- finalize BN for z2; zero pad cols; clear both stat sets ------------
__global__ void bn_fin(float* __restrict__ cs, float* __restrict__ csq,
                       const float* __restrict__ g, const float* __restrict__ be,
                       float* __restrict__ scale, float* __restrict__ shift,
                       int cols, int colspad, float invn,
                       float* __restrict__ extra, int nextra)
{
    int c = blockIdx.x * blockDim.x + threadIdx.x;
    if (c < nextra) { extra[c] = 0.f; extra[c + nextra] = 0.f; }   // clear cs1+csq1
    if (c >= colspad) return;
    if (c >= cols) { scale[c] = 0.f; shift[c] = 0.f; return; }
    float mu = cs[c] * invn;
    float var = csq[c] * invn - mu * mu;
    float rs = rsqrtf(var + 1e-5f);
    float sc = rs * g[c];
    scale[c] = sc;
    shift[c] = be[c] - mu * sc;
    cs[c] = 0.f;
    csq[c] = 0.f;
}

// ---------------- fused global_add_pool + BN2 affine + GroupNorm + head ----------------
__global__ __launch_bounds__(320) void pool_head(const u16* __restrict__ z2,
    const int* __restrict__ batch, int N,
    const float* __restrict__ sc, const float* __restrict__ sh,
    const float* __restrict__ w, const float* __restrict__ hb,
    float* __restrict__ out)
{
    __shared__ float red[320];
    int g = blockIdx.x;
    int t = threadIdx.x;
    int lo = 0, hi = N;
    while (lo < hi) { int mid = (lo + hi) >> 1; if (batch[mid] < g) lo = mid + 1; else hi = mid; }
    int start = lo;
    hi = N;
    while (lo < hi) { int mid = (lo + hi) >> 1; if (batch[mid] <= g) lo = mid + 1; else hi = mid; }
    int end = lo;

    float v = 0.f;
    if (t < DD) {
        float s = 0.f;
        for (int i = start; i < end; ++i) s += h2f(z2[(size_t)i * Z2LD + t]);
        v = sc[t] * s + (float)(end - start) * sh[t];
    }

    auto reduce = [&](float x) -> float {
        red[t] = x;
        __syncthreads();
        for (int off = 160; off >= 5; off >>= 1) {
            if (t < off) red[t] += red[t + off];
            __syncthreads();
        }
        float r = red[0] + red[1] + red[2] + red[3] + red[4];
        __syncthreads();
        return r;
    };

    float mean = reduce(v) * (1.f / (float)DD);
    float var  = reduce(v * v) * (1.f / (float)DD) - mean * mean;
    float rs = rsqrtf(var + 1e-5f);
    float contrib = (t < DD) ? (v - mean) * rs * w[t] : 0.f;
    float o = reduce(contrib);
    if (t == 0) out[g] = o + hb[0];
}

extern "C" void kernel_launch(void* const* d_in, const int* in_sizes, int n_in,
                              void* d_out, int out_size, void* d_ws, size_t ws_size,
                              hipStream_t stream)
{
    (void)n_in; (void)out_size; (void)ws_size;
    const int*   x         = (const int*)  d_in[0];
    const int*   edge_idx  = (const int*)  d_in[1];
    const int*   edge_attr = (const int*)  d_in[2];
    const int*   batch     = (const int*)  d_in[3];
    const float* atom_emb  = (const float*)d_in[4];
    const float* bond_emb  = (const float*)d_in[5];
    const float* eps       = (const float*)d_in[6];
    const float* W1        = (const float*)d_in[7];
    const float* b1        = (const float*)d_in[8];
    const float* g1        = (const float*)d_in[9];
    const float* be1       = (const float*)d_in[10];
    const float* W2        = (const float*)d_in[11];
    const float* b2        = (const float*)d_in[12];
    const float* g2        = (const float*)d_in[13];
    const float* be2       = (const float*)d_in[14];
    const float* head_w    = (const float*)d_in[15];
    const float* head_b    = (const float*)d_in[16];

    const int NN = in_sizes[3];          // nodes (20000)
    const int E  = in_sizes[1] / 2;      // edges (320000)
    const int rows256 = (NN + 255) / 256;       // 256-row GEMM blocks
    const int mpad = rows256 * 256;
    const float invn = 1.f / (float)NN;

    char* p = (char*)d_ws;
    auto alloc = [&](size_t bytes) { char* r = p; p += (bytes + 255) & ~(size_t)255; return r; };

    u16* z2g    = (u16*)  alloc((size_t)NN * Z2LD * 2);     // fp16 gather source / GEMM2 out
    u16* A1     = (u16*)  alloc((size_t)mpad * KP1 * 2);    // fp16 GIN-z (GEMM1 A)
    u16* Z1     = (u16*)  alloc((size_t)mpad * KP2 * 2);    // fp16 Z1 (GEMM2 A)
    u16* W1T    = (u16*)  alloc((size_t)LL * NP1 * KP1 * 2);
    u16* W2T    = (u16*)  alloc((size_t)LL * NP2 * KP2 * 2);
    u16* combo  = (u16*)  alloc((size_t)LL * 512 * CLD * 2);
    // stats: cs1/csq1 [608 each] for Z1; cs2/csq2 [304 each] for z2
    float* stats = (float*)alloc((608 * 2 + 304 * 2) * 4);
    float* cs1  = stats;
    float* csq1 = cs1 + 608;
    float* cs2  = csq1 + 608;
    float* csq2 = cs2 + 304;
    float* sc2  = (float*)alloc(Z2LD * 4);
    float* sh2  = (float*)alloc(Z2LD * 4);
    int* cnt    = (int*)  alloc((size_t)NN * 4 * 2);   // cnt+cursor contiguous
    int* cursor = cnt + NN;
    int* rowptr = (int*)  alloc((size_t)(NN + 1) * 4);
    int* rec    = (int*)  alloc((size_t)E * 4);

    const int* src = edge_idx;
    const int* dst = edge_idx + E;

    // ---- per-call setup ----
    hipMemsetAsync(cnt, 0, (size_t)NN * 2 * sizeof(int), stream);
    hipMemsetAsync(stats, 0, (608 * 2 + 304 * 2) * sizeof(float), stream);
    csr_count<<<512, 256, 0, stream>>>(dst, E, cnt);
    scan_kernel<<<1, 1024, 0, stream>>>(cnt, rowptr, NN);
    csr_fill<<<512, 256, 0, stream>>>(src, dst, edge_attr, rowptr, cursor, rec, E);
    w_prep_t<<<LL * (KP1 / 64) * (NP1 / 64), 256, 0, stream>>>(
        W1, DD, HH, KP1, NP1, KP1 / 64, W1T);
    w_prep_t<<<LL * ((KP2 + 63) / 64) * (NP2 / 64), 256, 0, stream>>>(
        W2, HH, DD, KP2, NP2, (KP2 + 63) / 64, W2T);
    atom_combo<<<NN + LL * 512, 320, 0, stream>>>(x, atom_emb, bond_emb, z2g, combo, NN);

    const int nwg1 = (NP1 / 128) * rows256;   // 5 * 79 = 395
    const int nwg2 = (NP2 / 128) * rows256;   // 3 * 79 = 237
    for (int l = 0; l < LL; ++l) {
        const u16* combo_l = combo + (size_t)l * 512 * CLD;
        if (l == 0)
            agg_kernel<false><<<NN, 256, 0, stream>>>(z2g, rec, rowptr, combo_l,
                nullptr, nullptr, eps, l, A1);
        else
            agg_kernel<true><<<NN, 256, 0, stream>>>(z2g, rec, rowptr, combo_l,
                sc2, sh2, eps, l, A1);

        gemm_rs<false, 2><<<nwg1, 512, 0, stream>>>(
            A1, KP1, W1T + (size_t)l * NP1 * KP1,
            b1 + (size_t)l * HH, nullptr, nullptr, nullptr, nullptr, invn,
            Z1, KP2, NN, HH, KP1 / 32, cs1, csq1, NP1 / 128, nwg1);

        gemm_rs<true, 2><<<nwg2, 512, 0, stream>>>(
            Z1, KP2, W2T + (size_t)l * NP2 * KP2,
            b2 + (size_t)l * DD,
            cs1, csq1, g1 + (size_t)l * HH, be1 + (size_t)l * HH, invn,
            z2g, Z2LD, NN, DD, KP2 / 32, cs2, csq2, NP2 / 128, nwg2);

        // finalize BN2 -> sc2/sh2 (for agg/pool); clears cs2/csq2 AND cs1/csq1
        bn_fin<<<3, 256, 0, stream>>>(cs2, csq2, g2 + (size_t)l * DD,
            be2 + (size_t)l * DD, sc2, sh2, DD, Z2LD, invn, cs1, 608);
    }

    pool_head<<<NGG, 320, 0, stream>>>(z2g, batch, NN, sc2, sh2, head_w, head_b,
                                       (float*)d_out);
}

// Round 21
// 641.844 us; speedup vs baseline: 1.1805x; 1.1805x over previous
//
#include <hip/hip_runtime.h>
#include <cstddef>
#include <cstdint>

#define DD 300
#define HH 600
#define LL 5
#define NGG 512
#define KP1 320     // padded K for GEMM1 (fp16 A row stride)
#define KP2 608     // padded K for GEMM2 (fp16 Z1 row stride)
#define NP1 640     // padded N of W1^T (600 -> 5 col-blocks of 128)
#define NP2 384     // padded N of W2^T (300 -> 3 col-blocks of 128)
#define Z2LD 304    // fp16 z2/h row stride
#define CLD 304     // fp16 combo row stride (16B-aligned rows)

typedef unsigned short u16;
typedef _Float16 f16x8 __attribute__((ext_vector_type(8)));
typedef _Float16 h2 __attribute__((ext_vector_type(2)));
typedef float f32x4 __attribute__((ext_vector_type(4)));

__device__ __forceinline__ u16 f2h(float v)
{
    _Float16 h = (_Float16)v; u16 u; __builtin_memcpy(&u, &h, 2); return u;
}
__device__ __forceinline__ float h2f(u16 u)
{
    _Float16 h; __builtin_memcpy(&h, &u, 2); return (float)h;
}

__device__ __forceinline__ void g2l16(const void* g, void* l)
{
    __builtin_amdgcn_global_load_lds(
        (const __attribute__((address_space(1))) void*)g,
        (__attribute__((address_space(3))) void*)l, 16, 0, 0);
}

// BatchNorm scale/shift from raw column stats
__device__ __forceinline__ void bn_from_stats(float s, float q, float g, float be,
                                              float invn, float& sc, float& sh)
{
    float mu = s * invn;
    float var = q * invn - mu * mu;
    float rs = rsqrtf(var + 1e-5f);
    sc = rs * g;
    sh = be - mu * sc;
}

// ---------------- fused Atom encoder + combo table builder ----------------
// blocks [0,N): atom encode node b -> z2; blocks [N, N+L*512): combo row (b-N)
__global__ __launch_bounds__(320) void atom_combo(const int* __restrict__ x,
    const float* __restrict__ emb, const float* __restrict__ bond,
    u16* __restrict__ z2, u16* __restrict__ combo, int N)
{
    int b = blockIdx.x;
    int t = threadIdx.x;
    if (b < N) {
        __shared__ int xi[9];
        if (t < 9) xi[t] = x[b * 9 + t] + t * 64;
        __syncthreads();
        if (t >= Z2LD) return;
        if (t >= DD) { z2[(size_t)b * Z2LD + t] = 0; return; }
        float s = 0.f;
#pragma unroll
        for (int f = 0; f < 9; ++f) s += emb[(size_t)xi[f] * DD + t];
        z2[(size_t)b * Z2LD + t] = f2h(s);
    } else {
        int blk = b - N;                // l*512 + code
        int l = blk >> 9, code = blk & 511;
        if (t >= CLD) return;
        u16 val = 0;
        if (t < DD) {
            const float* bl = bond + (size_t)l * 24 * DD;
            float v = bl[(size_t)(code & 7) * DD + t]
                    + bl[(size_t)(8 + ((code >> 3) & 7)) * DD + t]
                    + bl[(size_t)(16 + (code >> 6)) * DD + t];
            val = f2h(v);
        }
        combo[(size_t)blk * CLD + t] = val;
    }
}

// ---------------- CSR build ----------------
__global__ void csr_count(const int* __restrict__ dst, int E, int* __restrict__ cnt)
{
    int i = blockIdx.x * blockDim.x + threadIdx.x;
    int stride = gridDim.x * blockDim.x;
    for (; i < E; i += stride) atomicAdd(&cnt[dst[i]], 1);
}

__global__ __launch_bounds__(1024) void scan_kernel(const int* __restrict__ cnt,
    int* __restrict__ rowptr, int n)
{
    __shared__ int buf[1024];
    int t = threadIdx.x;
    int carry = 0;
    for (int base = 0; base < n; base += 1024) {
        int v = (base + t < n) ? cnt[base + t] : 0;
        buf[t] = v;
        __syncthreads();
        for (int off = 1; off < 1024; off <<= 1) {
            int x = (t >= off) ? buf[t - off] : 0;
            __syncthreads();
            buf[t] += x;
            __syncthreads();
        }
        if (base + t < n) rowptr[base + t] = buf[t] - v + carry;
        int total = buf[1023];
        __syncthreads();
        carry += total;
    }
    if (t == 0) rowptr[n] = carry;
}

__global__ void csr_fill(const int* __restrict__ src, const int* __restrict__ dst,
    const int* __restrict__ ea, const int* __restrict__ rowptr,
    int* __restrict__ cursor, int* __restrict__ rec, int E)
{
    int i = blockIdx.x * blockDim.x + threadIdx.x;
    int stride = gridDim.x * blockDim.x;
    for (; i < E; i += stride) {
        int d = dst[i];
        int pos = rowptr[d] + atomicAdd(&cursor[d], 1);
        int code = ea[i * 3] | (ea[i * 3 + 1] << 3) | (ea[i * 3 + 2] << 6);
        rec[pos] = src[i] | (code << 20);
    }
}

// ---------------- LDS-tiled weight transpose -> fp16, zero-padded ----------------
__global__ __launch_bounds__(256) void w_prep_t(const float* __restrict__ W,
    int K, int N, int KPp, int NPp, int ktiles, u16* __restrict__ Thi)
{
    __shared__ float tile[64][65];
    int ntiles = NPp >> 6;
    int blk = blockIdx.x;
    int l = blk / (ktiles * ntiles);
    int rem = blk % (ktiles * ntiles);
    int k0 = (rem / ntiles) << 6;
    int n0 = (rem % ntiles) << 6;
    int tn = threadIdx.x & 63;
    int tg = threadIdx.x >> 6;
    const float* Wl = W + (size_t)l * K * N;
    for (int kk = tg; kk < 64; kk += 4) {
        int gk = k0 + kk, gn = n0 + tn;
        tile[kk][tn] = (gk < K && gn < N) ? Wl[(size_t)gk * N + gn] : 0.f;
    }
    __syncthreads();
    for (int nn = tg; nn < 64; nn += 4) {
        int gn = n0 + nn, gk = k0 + tn;
        if (gk < KPp) {
            size_t o = ((size_t)l * NPp + gn) * KPp + gk;
            Thi[o] = f2h(tile[tn][nn]);
        }
    }
}

// ---------------- fused BN(prev)+ReLU + aggregate + GIN update -> fp16 A1 ----------------
// 256 threads; (edge-slot, chunk) decomposition: eo = t/38 (6 slots), ch = t%38.
// Inner math packed fp16 (v_pk_*); sc/sh PRECOMPUTED (the R13-proven prologue).
template <bool AFF>
__global__ __launch_bounds__(256) void agg_kernel(const u16* __restrict__ z2,
    const int* __restrict__ rec, const int* __restrict__ rowptr,
    const u16* __restrict__ combo_l,
    const float* __restrict__ sc, const float* __restrict__ sh,
    const float* __restrict__ eps, int l, u16* __restrict__ A1)
{
    __shared__ float part[6][304];
    int n = blockIdx.x;
    int t = threadIdx.x;
    int eo = t / 38, ch = t - eo * 38;
    int d0 = ch * 8;
    int beg = rowptr[n], end = rowptr[n + 1];

    if (eo < 6) {
        float acc[8] = {0.f, 0.f, 0.f, 0.f, 0.f, 0.f, 0.f, 0.f};
        h2 scp[4], shp[4];
        const h2 zz = {(_Float16)0.f, (_Float16)0.f};
        if (AFF) {
#pragma unroll
            for (int j = 0; j < 4; ++j) {
                scp[j] = (h2){(_Float16)sc[d0 + 2 * j], (_Float16)sc[d0 + 2 * j + 1]};
                shp[j] = (h2){(_Float16)sh[d0 + 2 * j], (_Float16)sh[d0 + 2 * j + 1]};
            }
        }
        int i = beg + eo;
        for (; i + 6 < end; i += 12) {         // unroll 2 (slot stride 6)
            int r0 = rec[i], r1 = rec[i + 6];
            uint4 hv0 = *(const uint4*)(z2 + (size_t)(r0 & 0xFFFFF) * Z2LD + d0);
            uint4 cv0 = *(const uint4*)(combo_l + (size_t)(((unsigned)r0) >> 20) * CLD + d0);
            uint4 hv1 = *(const uint4*)(z2 + (size_t)(r1 & 0xFFFFF) * Z2LD + d0);
            uint4 cv1 = *(const uint4*)(combo_l + (size_t)(((unsigned)r1) >> 20) * CLD + d0);
            const h2* hp0 = (const h2*)&hv0; const h2* cp0 = (const h2*)&cv0;
            const h2* hp1 = (const h2*)&hv1; const h2* cp1 = (const h2*)&cv1;
#pragma unroll
            for (int j = 0; j < 4; ++j) {
                h2 a0 = hp0[j], a1 = hp1[j];
                if (AFF) {
                    a0 = __builtin_elementwise_max(a0 * scp[j] + shp[j], zz);
                    a1 = __builtin_elementwise_max(a1 * scp[j] + shp[j], zz);
                }
                h2 m0 = __builtin_elementwise_max(a0 + cp0[j], zz);
                h2 m1 = __builtin_elementwise_max(a1 + cp1[j], zz);
                acc[2 * j]     += (float)m0.x + (float)m1.x;
                acc[2 * j + 1] += (float)m0.y + (float)m1.y;
            }
        }
        for (; i < end; i += 6) {
            int r0 = rec[i];
            uint4 hv0 = *(const uint4*)(z2 + (size_t)(r0 & 0xFFFFF) * Z2LD + d0);
            uint4 cv0 = *(const uint4*)(combo_l + (size_t)(((unsigned)r0) >> 20) * CLD + d0);
            const h2* hp0 = (const h2*)&hv0; const h2* cp0 = (const h2*)&cv0;
#pragma unroll
            for (int j = 0; j < 4; ++j) {
                h2 a0 = hp0[j];
                if (AFF) a0 = __builtin_elementwise_max(a0 * scp[j] + shp[j], zz);
                h2 m0 = __builtin_elementwise_max(a0 + cp0[j], zz);
                acc[2 * j]     += (float)m0.x;
                acc[2 * j + 1] += (float)m0.y;
            }
        }
        *(float4*)&part[eo][d0]     = *(const float4*)&acc[0];
        *(float4*)&part[eo][d0 + 4] = *(const float4*)&acc[4];
    }
    __syncthreads();

    if (t < 152) {
        float se = 1.0f + eps[l];
        int d = t * 2;
#pragma unroll
        for (int k = 0; k < 2; ++k) {
            int dd = d + k;
            float s = part[0][dd] + part[1][dd] + part[2][dd]
                    + part[3][dd] + part[4][dd] + part[5][dd];
            float hn = h2f(z2[(size_t)n * Z2LD + dd]);
            if (AFF) hn = fmaxf(fmaf(hn, sc[dd], sh[dd]), 0.f);
            A1[(size_t)n * KP1 + dd] = f2h(fmaf(se, hn, s));
        }
    } else if (t < 160) {
        int d = 304 + (t - 152) * 2;
        A1[(size_t)n * KP1 + d] = 0;
        A1[(size_t)n * KP1 + d + 1] = 0;
    }
}

// ---------------- f16 MFMA GEMM, 3-buffer B + 3-deep A pipeline, counted waits --------
// R18 structure. FUSE: BN1+ReLU on A computed inline FROM RAW STATS (R11-proven prologue).
template <bool FUSE>
__global__ __launch_bounds__(512, 4) void gemm_rs(
    const u16* __restrict__ Af, int lda,
    const u16* __restrict__ Bw,
    const float* __restrict__ bias,
    const float* __restrict__ csA, const float* __restrict__ csqA,
    const float* __restrict__ gA, const float* __restrict__ beA, float invn,
    u16* __restrict__ O, int ldc, int M, int N, int ksteps,
    float* __restrict__ cs, float* __restrict__ csq, int ncol, int nwg)
{
    __shared__ __align__(16) u16 As[2][4][128][8];
    __shared__ __align__(16) u16 Bs[3][4][128][8];
    __shared__ float sc_s[FUSE ? 640 : 1], sh_s[FUSE ? 640 : 1];

    const int t = threadIdx.x;
    const int lane = t & 63, w = t >> 6;
    const int l15 = lane & 15, l4 = lane >> 4;
    const int wr = w >> 2, wc = w & 3;          // wave tile: 64 rows x 32 cols

    // bijective XCD swizzle (m204): contiguous wgid chunk per XCD
    int orig = blockIdx.x;
    int q8 = nwg >> 3, r8 = nwg & 7;
    int xcd = orig & 7, i8 = orig >> 3;
    int wgid = (xcd < r8 ? xcd * (q8 + 1) : r8 * (q8 + 1) + (xcd - r8) * q8) + i8;
    const int col0 = (wgid % ncol) * 128;
    const int row0 = (wgid / ncol) * 128;

    if (FUSE) {
        for (int c = t; c < lda; c += 512) {
            float a = 0.f, b = 0.f;
            if (c < HH) bn_from_stats(csA[c], csqA[c], gA[c], beA[c], invn, a, b);
            sc_s[c] = a; sh_s[c] = b;
        }
    }

    const int arow = t >> 2;            // 0..127
    const int kg   = t & 3;             // 0..3
    const int k8   = kg * 8;
    const u16* aptr = Af + (size_t)(row0 + arow) * lda + k8;

    const int bkg = w >> 1, bch = w & 1;
    const u16* bptr = Bw + (size_t)(col0 + bch * 64 + lane) * lda + bkg * 8;

    auto loadAv = [&](int ks, uint4& pv) {
        pv = *(const uint4*)(aptr + ks * 32);
    };
    auto issueB = [&](int ks, int buf) {
        g2l16(bptr + ks * 32, &Bs[buf][bkg][bch * 64][0]);
    };
    auto writeAv = [&](int ks, int buf, uint4& pv) {
        if (FUSE) {
            const u16* hp = (const u16*)&pv;
            u16 oh[8];
#pragma unroll
            for (int j = 0; j < 8; ++j) {
                int c = ks * 32 + k8 + j;
                float xv = fmaxf(fmaf(h2f(hp[j]), sc_s[c], sh_s[c]), 0.f);
                oh[j] = f2h(xv);
            }
            *(uint4*)&As[buf][kg][arow][0] = *(const uint4*)oh;
        } else {
            *(uint4*)&As[buf][kg][arow][0] = pv;
        }
    };

    f32x4 acc[4][2];
#pragma unroll
    for (int i = 0; i < 4; ++i)
#pragma unroll
        for (int j = 0; j < 2; ++j) acc[i][j] = (f32x4){0.f, 0.f, 0.f, 0.f};

    uint4 pvA, pvB, pvC;
    __syncthreads();                    // sc_s visible
    // prologue (ksteps >= 3 always): issue order A(0), B(0), B(1), A(1), A(2)
    loadAv(0, pvA);
    issueB(0, 0);
    issueB(1, 1);
    loadAv(1, pvB);
    loadAv(2, pvC);
    writeAv(0, 0, pvA);                 // compiler waits for A(0) (vmcnt(4))
    asm volatile("s_waitcnt vmcnt(3) lgkmcnt(0)" ::: "memory");  // B(0)+ds_write done
    __builtin_amdgcn_s_barrier();

    int cur = 0, rb = 0, tb = 2;
    auto body = [&](int ks, uint4& hold, uint4& fill) {
        const bool more1 = (ks + 1 < ksteps), more2 = (ks + 2 < ksteps),
                   more3 = (ks + 3 < ksteps);
        if (more2) issueB(ks + 2, tb);
        if (more3) loadAv(ks + 3, fill);

        f16x8 a[4], b[2];
#pragma unroll
        for (int i = 0; i < 4; ++i) {
            int r = wr * 64 + i * 16 + l15;
            a[i] = *(const f16x8*)As[cur][l4][r];
        }
#pragma unroll
        for (int i = 0; i < 2; ++i) {
            int c = wc * 32 + i * 16 + l15;
            b[i] = *(const f16x8*)Bs[rb][l4][c];
        }
#pragma unroll
        for (int mi = 0; mi < 4; ++mi)
#pragma unroll
            for (int ni = 0; ni < 2; ++ni)
                acc[mi][ni] = __builtin_amdgcn_mfma_f32_16x16x32_f16(a[mi], b[ni], acc[mi][ni], 0, 0, 0);

        if (more1) {
            writeAv(ks + 1, cur ^ 1, hold);   // implicit wait for A(ks+1)
            // drain B(ks+1) before barrier; younger loads: A(ks+2),B(ks+2),A(ks+3)
            if (more3)      asm volatile("s_waitcnt vmcnt(3) lgkmcnt(0)" ::: "memory");
            else if (more2) asm volatile("s_waitcnt vmcnt(2) lgkmcnt(0)" ::: "memory");
            else            asm volatile("s_waitcnt vmcnt(0) lgkmcnt(0)" ::: "memory");
            __builtin_amdgcn_s_barrier();
        }
        cur ^= 1;
        rb = (rb == 2) ? 0 : rb + 1;
        tb = (tb == 2) ? 0 : tb + 1;
    };
    for (int k = 0; k < ksteps; k += 3) {
        body(k, pvB, pvA);
        if (k + 1 < ksteps) body(k + 1, pvC, pvB);
        if (k + 2 < ksteps) body(k + 2, pvA, pvC);
    }

    // epilogue: + bias, fp16 store + fused column stats
    float colS[2] = {0.f, 0.f}, colQ[2] = {0.f, 0.f};
#pragma unroll
    for (int ni = 0; ni < 2; ++ni) {
        int gc = col0 + wc * 32 + ni * 16 + l15;
        float bb = (gc < N) ? bias[gc] : 0.f;
#pragma unroll
        for (int mi = 0; mi < 4; ++mi)
#pragma unroll
            for (int r = 0; r < 4; ++r) {
                int gr = row0 + wr * 64 + mi * 16 + l4 * 4 + r;
                if (gr >= M) continue;
                if (gc < N) {
                    float val = acc[mi][ni][r] + bb;
                    O[(size_t)gr * ldc + gc] = f2h(val);
                    colS[ni] += val;
                    colQ[ni] += val * val;
                } else if (gc < ldc) {
                    O[(size_t)gr * ldc + gc] = 0;
                }
            }
    }
#pragma unroll
    for (int ni = 0; ni < 2; ++ni) {
        float s = colS[ni], q = colQ[ni];
        s += __shfl_xor(s, 16); s += __shfl_xor(s, 32);
        q += __shfl_xor(q, 16); q += __shfl_xor(q, 32);
        int gc = col0 + wc * 32 + ni * 16 + l15;
        if (l4 == 0 && gc < N) {
            atomicAdd(&cs[gc], s);
            atomicAdd(&csq[gc], q);
        }
    }
}

// ---------------- finalize BN for z2; zero pad cols; clear both stat sets ------------
__global__ void bn_fin(float* __restrict__ cs, float* __restrict__ csq,
                       const float* __restrict__ g, const float* __restrict__ be,
                       float* __restrict__ scale, float* __restrict__ shift,
                       int cols, int colspad, float invn,
                       float* __restrict__ extra, int nextra)
{
    int c = blockIdx.x * blockDim.x + threadIdx.x;
    if (c < nextra) { extra[c] = 0.f; extra[c + nextra] = 0.f; }   // clear cs1+csq1
    if (c >= colspad) return;
    if (c >= cols) { scale[c] = 0.f; shift[c] = 0.f; return; }
    float mu = cs[c] * invn;
    float var = csq[c] * invn - mu * mu;
    float rs = rsqrtf(var + 1e-5f);
    float sc = rs * g[c];
    scale[c] = sc;
    shift[c] = be[c] - mu * sc;
    cs[c] = 0.f;
    csq[c] = 0.f;
}

// ---------------- fused global_add_pool + BN2 affine + GroupNorm + head ----------------
__global__ __launch_bounds__(320) void pool_head(const u16* __restrict__ z2,
    const int* __restrict__ batch, int N,
    const float* __restrict__ sc, const float* __restrict__ sh,
    const float* __restrict__ w, const float* __restrict__ hb,
    float* __restrict__ out)
{
    __shared__ float red[320];
    int g = blockIdx.x;
    int t = threadIdx.x;
    int lo = 0, hi = N;
    while (lo < hi) { int mid = (lo + hi) >> 1; if (batch[mid] < g) lo = mid + 1; else hi = mid; }
    int start = lo;
    hi = N;
    while (lo < hi) { int mid = (lo + hi) >> 1; if (batch[mid] <= g) lo = mid + 1; else hi = mid; }
    int end = lo;

    float v = 0.f;
    if (t < DD) {
        float s = 0.f;
        for (int i = start; i < end; ++i) s += h2f(z2[(size_t)i * Z2LD + t]);
        v = sc[t] * s + (float)(end - start) * sh[t];
    }

    auto reduce = [&](float x) -> float {
        red[t] = x;
        __syncthreads();
        for (int off = 160; off >= 5; off >>= 1) {
            if (t < off) red[t] += red[t + off];
            __syncthreads();
        }
        float r = red[0] + red[1] + red[2] + red[3] + red[4];
        __syncthreads();
        return r;
    };

    float mean = reduce(v) * (1.f / (float)DD);
    float var  = reduce(v * v) * (1.f / (float)DD) - mean * mean;
    float rs = rsqrtf(var + 1e-5f);
    float contrib = (t < DD) ? (v - mean) * rs * w[t] : 0.f;
    float o = reduce(contrib);
    if (t == 0) out[g] = o + hb[0];
}

extern "C" void kernel_launch(void* const* d_in, const int* in_sizes, int n_in,
                              void* d_out, int out_size, void* d_ws, size_t ws_size,
                              hipStream_t stream)
{
    (void)n_in; (void)out_size; (void)ws_size;
    const int*   x         = (const int*)  d_in[0];
    const int*   edge_idx  = (const int*)  d_in[1];
    const int*   edge_attr = (const int*)  d_in[2];
    const int*   batch     = (const int*)  d_in[3];
    const float* atom_emb  = (const float*)d_in[4];
    const float* bond_emb  = (const float*)d_in[5];
    const float* eps       = (const float*)d_in[6];
    const float* W1        = (const float*)d_in[7];
    const float* b1        = (const float*)d_in[8];
    const float* g1        = (const float*)d_in[9];
    const float* be1       = (const float*)d_in[10];
    const float* W2        = (const float*)d_in[11];
    const float* b2        = (const float*)d_in[12];
    const float* g2        = (const float*)d_in[13];
    const float* be2       = (const float*)d_in[14];
    const float* head_w    = (const float*)d_in[15];
    const float* head_b    = (const float*)d_in[16];

    const int NN = in_sizes[3];          // nodes (20000)
    const int E  = in_sizes[1] / 2;      // edges (320000)
    const int gm = (NN + 127) / 128;     // row-blocks
    const int mpad = gm * 128;
    const float invn = 1.f / (float)NN;

    char* p = (char*)d_ws;
    auto alloc = [&](size_t bytes) { char* r = p; p += (bytes + 255) & ~(size_t)255; return r; };

    u16* z2g    = (u16*)  alloc((size_t)NN * Z2LD * 2);     // fp16 gather source / GEMM2 out
    u16* A1     = (u16*)  alloc((size_t)mpad * KP1 * 2);    // fp16 GIN-z (GEMM1 A)
    u16* Z1     = (u16*)  alloc((size_t)mpad * KP2 * 2);    // fp16 Z1 (GEMM2 A)
    u16* W1T    = (u16*)  alloc((size_t)LL * NP1 * KP1 * 2);
    u16* W2T    = (u16*)  alloc((size_t)LL * NP2 * KP2 * 2);
    u16* combo  = (u16*)  alloc((size_t)LL * 512 * CLD * 2);
    // stats: cs1/csq1 [608 each] for Z1; cs2/csq2 [304 each] for z2 (contiguous, 1 memset)
    float* stats = (float*)alloc((608 * 2 + 304 * 2) * 4);
    float* cs1  = stats;
    float* csq1 = cs1 + 608;
    float* cs2  = csq1 + 608;
    float* csq2 = cs2 + 304;
    float* sc2  = (float*)alloc(Z2LD * 4);
    float* sh2  = (float*)alloc(Z2LD * 4);
    int* cnt    = (int*)  alloc((size_t)NN * 4 * 2);   // cnt+cursor contiguous
    int* cursor = cnt + NN;
    int* rowptr = (int*)  alloc((size_t)(NN + 1) * 4);
    int* rec    = (int*)  alloc((size_t)E * 4);

    const int* src = edge_idx;
    const int* dst = edge_idx + E;

    // ---- per-call setup ----
    hipMemsetAsync(cnt, 0, (size_t)NN * 2 * sizeof(int), stream);
    hipMemsetAsync(stats, 0, (608 * 2 + 304 * 2) * sizeof(float), stream);
    csr_count<<<512, 256, 0, stream>>>(dst, E, cnt);
    scan_kernel<<<1, 1024, 0, stream>>>(cnt, rowptr, NN);
    csr_fill<<<512, 256, 0, stream>>>(src, dst, edge_attr, rowptr, cursor, rec, E);
    w_prep_t<<<LL * (KP1 / 64) * (NP1 / 64), 256, 0, stream>>>(
        W1, DD, HH, KP1, NP1, KP1 / 64, W1T);
    w_prep_t<<<LL * ((KP2 + 63) / 64) * (NP2 / 64), 256, 0, stream>>>(
        W2, HH, DD, KP2, NP2, (KP2 + 63) / 64, W2T);
    atom_combo<<<NN + LL * 512, 320, 0, stream>>>(x, atom_emb, bond_emb, z2g, combo, NN);

    const int nwg1 = (NP1 / 128) * gm;
    const int nwg2 = (NP2 / 128) * gm;
    for (int l = 0; l < LL; ++l) {
        const u16* combo_l = combo + (size_t)l * 512 * CLD;
        if (l == 0)
            agg_kernel<false><<<NN, 256, 0, stream>>>(z2g, rec, rowptr, combo_l,
                nullptr, nullptr, eps, l, A1);
        else
            agg_kernel<true><<<NN, 256, 0, stream>>>(z2g, rec, rowptr, combo_l,
                sc2, sh2, eps, l, A1);

        gemm_rs<false><<<nwg1, 512, 0, stream>>>(
            A1, KP1, W1T + (size_t)l * NP1 * KP1,
            b1 + (size_t)l * HH, nullptr, nullptr, nullptr, nullptr, invn,
            Z1, KP2, NN, HH, KP1 / 32, cs1, csq1, NP1 / 128, nwg1);

        gemm_rs<true><<<nwg2, 512, 0, stream>>>(
            Z1, KP2, W2T + (size_t)l * NP2 * KP2,
            b2 + (size_t)l * DD,
            cs1, csq1, g1 + (size_t)l * HH, be1 + (size_t)l * HH, invn,
            z2g, Z2LD, NN, DD, KP2 / 32, cs2, csq2, NP2 / 128, nwg2);

        // finalize BN2 -> sc2/sh2 (for agg/pool); clears cs2/csq2 AND cs1/csq1
        bn_fin<<<3, 256, 0, stream>>>(cs2, csq2, g2 + (size_t)l * DD,
            be2 + (size_t)l * DD, sc2, sh2, DD, Z2LD, invn, cs1, 608);
    }

    pool_head<<<NGG, 320, 0, stream>>>(z2g, batch, NN, sc2, sh2, head_w, head_b,
                                       (float*)d_out);
}